// Round 4
// baseline (336.422 us; speedup 1.0000x reference)
//
#include <hip/hip_runtime.h>

constexpr int DIMN = 160;
constexpr int VOL  = DIMN * DIMN * DIMN;   // 4,096,000
constexpr int BATCH = 2;
constexpr long long NPTS = (long long)BATCH * VOL;

constexpr int TH = 8;      // H rows per block
constexpr int TZ = 8;      // output z planes per block
constexpr int ROWS = TH + 4;
constexpr int PADW = 164;  // 160 + 2 pad each side; 164 % 32 == 4 -> good bank spread

template <bool B> struct BoolC { static constexpr bool value = B; };

__device__ __forceinline__ int iclampi(int v, int lo, int hi) {
    return v < lo ? lo : (v > hi ? hi : v);
}

// ---------------------------------------------------------------------------
// Kernel A: accumulate-formulation 5x5x5 conv, replicate pad, z-march.
// Block (320): 40 w-strips x 8 h-rows. Each z-step stages one x plane into a
// 2-slot LDS ring and scatters it into 5 register accumulator planes.
// ---------------------------------------------------------------------------
__global__ __launch_bounds__(320) void conv3d_acc(
    const float* __restrict__ x, const float* __restrict__ w,
    float* __restrict__ y)
{
    __shared__ float xs[2][ROWS][PADW];
    __shared__ float wl[125];

    const int tid = threadIdx.x;
    if (tid < 125) wl[tid] = w[tid];
    __syncthreads();

    float wreg[125];
#pragma unroll
    for (int i = 0; i < 125; ++i) wreg[i] = wl[i];

    const int txw = tid % 40;   // strip (4 floats) in W
    const int tyh = tid / 40;   // 0..7
    const int h0 = blockIdx.x * TH;
    const int z0 = blockIdx.y * TZ;
    const int b  = blockIdx.z;
    const float* xb = x + (size_t)b * VOL;

    // staging task geometry: task1 = (row ra, col ca); task2 = (ra+8, ca) for tid<160
    const int ca = tid % 40;
    const int ra = tid / 40;        // 0..7
    const bool two = (tid < 160);   // rows 8..11
    const int ha  = iclampi(h0 - 2 + ra, 0, DIMN - 1);
    const int hb  = iclampi(h0 - 2 + ra + 8, 0, DIMN - 1);

    auto wr_task = [&](int slot, int r, int c, float4 v) {
        float* dst = &xs[slot][r][4 * c + 2];
        *(float2*)(dst)     = make_float2(v.x, v.y);
        *(float2*)(dst + 2) = make_float2(v.z, v.w);
        if (c == 0)  *(float2*)(&xs[slot][r][0])   = make_float2(v.x, v.x);
        if (c == 39) *(float2*)(&xs[slot][r][162]) = make_float2(v.w, v.w);
    };

    float acc[5][4];
#pragma unroll
    for (int j = 0; j < 5; ++j)
#pragma unroll
        for (int t = 0; t < 4; ++t) acc[j][t] = 0.f;

    // prologue: stage plane z0-2 into slot 0
    {
        const int zz = iclampi(z0 - 2, 0, DIMN - 1);
        float4 va = *(const float4*)(xb + ((size_t)zz * DIMN + ha) * DIMN + 4 * ca);
        wr_task(0, ra, ca, va);
        if (two) {
            float4 vb = *(const float4*)(xb + ((size_t)zz * DIMN + hb) * DIMN + 4 * ca);
            wr_task(0, ra + 8, ca, vb);
        }
    }
    __syncthreads();

    for (int k = 0; k < TZ + 4; ++k) {
        const int zi = z0 - 2 + k;
        const int slot = k & 1;
        const bool lastk = (k == TZ + 3);

        // ---- issue prefetch loads for plane zi+1 ----
        float4 fa, fb;
        if (!lastk) {
            const int zz = iclampi(zi + 1, 0, DIMN - 1);
            fa = *(const float4*)(xb + ((size_t)zz * DIMN + ha) * DIMN + 4 * ca);
            if (two)
                fb = *(const float4*)(xb + ((size_t)zz * DIMN + hb) * DIMN + 4 * ca);
        }

        // ---- compute contributions of plane zi from xs[slot] ----
        const bool full = (k >= 4) && (k <= TZ - 1);
        auto body = [&](auto FC) {
            constexpr bool FULL = decltype(FC)::value;
#pragma unroll
            for (int ky = 0; ky < 5; ++ky) {
                const float* src = &xs[slot][tyh + ky][4 * txw];
                float4 p0 = *(const float4*)(src);
                float4 p1 = *(const float4*)(src + 4);
                float v[8] = {p0.x, p0.y, p0.z, p0.w, p1.x, p1.y, p1.z, p1.w};
#pragma unroll
                for (int kz = 0; kz < 5; ++kz) {
                    if (!FULL) {
                        if (kz < k - (TZ - 1) || kz > k) continue;  // z' outside chunk
                    }
                    const int j = 4 - kz;
#pragma unroll
                    for (int kx = 0; kx < 5; ++kx) {
                        const float wv = wreg[(kz * 5 + ky) * 5 + kx];
#pragma unroll
                        for (int t = 0; t < 4; ++t)
                            acc[j][t] = fmaf(wv, v[kx + t], acc[j][t]);
                    }
                }
            }
        };
        if (full) body(BoolC<true>{}); else body(BoolC<false>{});

        // ---- output plane zo = zi-2 (complete after this step) ----
        const int zo = zi - 2;
        if (zo >= z0) {
            float4 o = make_float4(acc[0][0], acc[0][1], acc[0][2], acc[0][3]);
            *(float4*)(y + (((size_t)b * DIMN + zo) * DIMN + (h0 + tyh)) * DIMN + 4 * txw) = o;
        }

        // ---- shift accumulator ring ----
#pragma unroll
        for (int j = 0; j < 4; ++j)
#pragma unroll
            for (int t = 0; t < 4; ++t) acc[j][t] = acc[j + 1][t];
#pragma unroll
        for (int t = 0; t < 4; ++t) acc[4][t] = 0.f;

        // ---- write prefetched plane into the other slot ----
        if (!lastk) {
            const int ns = slot ^ 1;
            wr_task(ns, ra, ca, fa);
            if (two) wr_task(ns, ra + 8, ca, fb);
        }
        __syncthreads();
    }
}

// ---------------------------------------------------------------------------
// Kernel B: Hessian (jnp.gradient twice) + MLP, strip-4 vectorized.
// ---------------------------------------------------------------------------
__global__ __launch_bounds__(256) void hess_mlp4(
    const float* __restrict__ Yg,
    const float* __restrict__ w1, const float* __restrict__ b1,
    const float* __restrict__ w2, const float* __restrict__ b2,
    float* __restrict__ out)
{
    const int sid = blockIdx.x * 256 + threadIdx.x;   // strip id, < 2,048,000
    const int rrow = sid / 40;                        // row over (b,z,y)
    const int x0 = (sid - rrow * 40) * 4;
    const int b = rrow / (DIMN * DIMN);
    int rem = rrow - b * (DIMN * DIMN);
    const int z = rem / DIMN;
    const int y = rem - z * DIMN;

    const float* Yb = Yg + (size_t)b * VOL;
    const int zp1 = min(z + 1, DIMN - 1), zm1 = max(z - 1, 0);
    const int zp2 = min(z + 2, DIMN - 1), zm2 = max(z - 2, 0);
    const int yp1 = min(y + 1, DIMN - 1), ym1 = max(y - 1, 0);
    const int yp2 = min(y + 2, DIMN - 1), ym2 = max(y - 2, 0);

    auto rowp = [&](int zz, int yy) { return Yb + ((size_t)zz * DIMN + yy) * DIMN; };

    const int xl = max(x0 - 2, 0);
    const int xr = (x0 < DIMN - 4) ? (x0 + 4) : (DIMN - 2);
    const bool xL = (x0 > 0), xR = (x0 < DIMN - 4);

    // center row (z,y): width 8
    const float* Rc = rowp(z, y);
    float4 Cc = *(const float4*)(Rc + x0);
    float2 Cl = *(const float2*)(Rc + xl);
    float2 Cr = *(const float2*)(Rc + xr);
    // width-6 rows
    const float* Rzp = rowp(zp1, y);
    float4 Pzc = *(const float4*)(Rzp + x0);
    float2 Pzl = *(const float2*)(Rzp + xl);
    float2 Pzr = *(const float2*)(Rzp + xr);
    const float* Rzm = rowp(zm1, y);
    float4 Mzc = *(const float4*)(Rzm + x0);
    float2 Mzl = *(const float2*)(Rzm + xl);
    float2 Mzr = *(const float2*)(Rzm + xr);
    const float* Ryp = rowp(z, yp1);
    float4 Pyc = *(const float4*)(Ryp + x0);
    float2 Pyl = *(const float2*)(Ryp + xl);
    float2 Pyr = *(const float2*)(Ryp + xr);
    const float* Rym = rowp(z, ym1);
    float4 Myc = *(const float4*)(Rym + x0);
    float2 Myl = *(const float2*)(Rym + xl);
    float2 Myr = *(const float2*)(Rym + xr);
    // center-only rows
    float4 Z2p = *(const float4*)(rowp(zp2, y) + x0);
    float4 Z2m = *(const float4*)(rowp(zm2, y) + x0);
    float4 Y2p = *(const float4*)(rowp(z, yp2) + x0);
    float4 Y2m = *(const float4*)(rowp(z, ym2) + x0);
    float4 Dpp = *(const float4*)(rowp(zp1, yp1) + x0);
    float4 Dpm = *(const float4*)(rowp(zp1, ym1) + x0);
    float4 Dmp = *(const float4*)(rowp(zm1, yp1) + x0);
    float4 Dmm = *(const float4*)(rowp(zm1, ym1) + x0);

    // value arrays (compile-time indexed after unroll)
    float V[8];   // center row, V[i] <-> x offset i-2 (clamped)
    V[0] = Cl.x;
    V[1] = xL ? Cl.y : Cl.x;
    V[2] = Cc.x; V[3] = Cc.y; V[4] = Cc.z; V[5] = Cc.w;
    V[6] = xR ? Cr.x : Cr.y;
    V[7] = Cr.y;
    float PZ[6], MZ[6], PY[6], MY[6];  // idx i <-> x offset i-1 (clamped)
    PZ[0] = xL ? Pzl.y : Pzl.x; PZ[1] = Pzc.x; PZ[2] = Pzc.y; PZ[3] = Pzc.z; PZ[4] = Pzc.w; PZ[5] = xR ? Pzr.x : Pzr.y;
    MZ[0] = xL ? Mzl.y : Mzl.x; MZ[1] = Mzc.x; MZ[2] = Mzc.y; MZ[3] = Mzc.z; MZ[4] = Mzc.w; MZ[5] = xR ? Mzr.x : Mzr.y;
    PY[0] = xL ? Pyl.y : Pyl.x; PY[1] = Pyc.x; PY[2] = Pyc.y; PY[3] = Pyc.z; PY[4] = Pyc.w; PY[5] = xR ? Pyr.x : Pyr.y;
    MY[0] = xL ? Myl.y : Myl.x; MY[1] = Myc.x; MY[2] = Myc.y; MY[3] = Myc.z; MY[4] = Myc.w; MY[5] = xR ? Myr.x : Myr.y;
    float C4[4] = {Cc.x, Cc.y, Cc.z, Cc.w};
    float Z2P[4] = {Z2p.x, Z2p.y, Z2p.z, Z2p.w};
    float Z2M[4] = {Z2m.x, Z2m.y, Z2m.z, Z2m.w};
    float Y2P[4] = {Y2p.x, Y2p.y, Y2p.z, Y2p.w};
    float Y2M[4] = {Y2m.x, Y2m.y, Y2m.z, Y2m.w};
    float DPP[4] = {Dpp.x, Dpp.y, Dpp.z, Dpp.w};
    float DPM[4] = {Dpm.x, Dpm.y, Dpm.z, Dpm.w};
    float DMP[4] = {Dmp.x, Dmp.y, Dmp.z, Dmp.w};
    float DMM[4] = {Dmm.x, Dmm.y, Dmm.z, Dmm.w};

    const float sz1 = (z > 0 && z < DIMN - 1) ? 0.5f : 1.0f;
    const float szp = (z < DIMN - 2) ? 0.5f : 1.0f;
    const float szm = (z > 1) ? 0.5f : 1.0f;
    const float sy1 = (y > 0 && y < DIMN - 1) ? 0.5f : 1.0f;
    const float syp = (y < DIMN - 2) ? 0.5f : 1.0f;
    const float sym = (y > 1) ? 0.5f : 1.0f;
    const bool zTop = (z == DIMN - 1), zBot = (z == 0);
    const bool yTop = (y == DIMN - 1), yBot = (y == 0);

    float res[4];
#pragma unroll
    for (int t = 0; t < 4; ++t) {
        const int xx = x0 + t;
        const float sx1 = (xx > 0 && xx < DIMN - 1) ? 0.5f : 1.0f;
        const float sxp = (xx < DIMN - 2) ? 0.5f : 1.0f;
        const float sxm = (xx > 1) ? 0.5f : 1.0f;

        float h0v, h1v, h2v, h3v, h4v, h5v;
        {   // h0: d2/dz2
            const float B0 = zTop ? MZ[t + 1] : C4[t];   // row (zp1-1) center value
            const float C0 = zBot ? PZ[t + 1] : C4[t];   // row (zm1+1) center value
            h0v = sz1 * (szp * (Z2P[t] - B0) - szm * (C0 - Z2M[t]));
        }
        h1v = sy1 * sz1 * ((DPP[t] - DMP[t]) - (DPM[t] - DMM[t]));
        h2v = sx1 * sz1 * ((PZ[t + 2] - MZ[t + 2]) - (PZ[t] - MZ[t]));
        {   // h3: d2/dy2
            const float B3 = yTop ? MY[t + 1] : C4[t];
            const float C3 = yBot ? PY[t + 1] : C4[t];
            h3v = sy1 * (syp * (Y2P[t] - B3) - sym * (C3 - Y2M[t]));
        }
        h4v = sx1 * sy1 * ((PY[t + 2] - MY[t + 2]) - (PY[t] - MY[t]));
        {   // h5: d2/dx2
            const float aP = (xx == DIMN - 1) ? V[t + 1] : V[t + 2];
            const float cM = (xx == 0) ? V[t + 3] : V[t + 2];
            const float GXp = sxp * (V[t + 4] - aP);
            const float GXm = sxm * (cM - V[t]);
            h5v = sx1 * (GXp - GXm);
        }

        float o = b2[0];
#pragma unroll
        for (int oo = 0; oo < 10; ++oo) {
            float a = b1[oo];
            a = fmaf(h0v, w1[oo * 6 + 0], a);
            a = fmaf(h1v, w1[oo * 6 + 1], a);
            a = fmaf(h2v, w1[oo * 6 + 2], a);
            a = fmaf(h3v, w1[oo * 6 + 3], a);
            a = fmaf(h4v, w1[oo * 6 + 4], a);
            a = fmaf(h5v, w1[oo * 6 + 5], a);
            a = fmaxf(a, 0.f);
            o = fmaf(a, w2[oo], o);
        }
        res[t] = 1.0f / (1.0f + __expf(-o));
    }

    *(float4*)(out + (size_t)sid * 4) =
        make_float4(res[0], res[1], res[2], res[3]);
}

// ---------------------------------------------------------------------------
extern "C" void kernel_launch(void* const* d_in, const int* in_sizes, int n_in,
                              void* d_out, int out_size, void* d_ws, size_t ws_size,
                              hipStream_t stream)
{
    const float* x  = (const float*)d_in[0];
    const float* cw = (const float*)d_in[1];
    const float* w1 = (const float*)d_in[2];
    const float* b1 = (const float*)d_in[3];
    const float* w2 = (const float*)d_in[4];
    const float* b2 = (const float*)d_in[5];
    float* outp = (float*)d_out;
    float* yws  = (float*)d_ws;

    dim3 grdA(DIMN / TH, DIMN / TZ, BATCH);   // 20 x 20 x 2 = 800 blocks
    conv3d_acc<<<grdA, 320, 0, stream>>>(x, cw, yws);

    const int nblkB = (int)(NPTS / 4 / 256);  // 8000
    hess_mlp4<<<nblkB, 256, 0, stream>>>(yws, w1, b1, w2, b2, outp);
}

// Round 5
// 174.520 us; speedup vs baseline: 1.9277x; 1.9277x over previous
//
#include <hip/hip_runtime.h>

constexpr int DIMN = 160;
constexpr int VOL  = DIMN * DIMN * DIMN;   // 4,096,000
constexpr int BATCH = 2;
constexpr long long NPTS = (long long)BATCH * VOL;

__device__ __forceinline__ int iclampi(int v, int lo, int hi) {
    return v < lo ? lo : (v > hi ? hi : v);
}

// ---------------------------------------------------------------------------
// Kernel A: gather-formulation 5x5x5 conv, replicate pad.
// Thread: 8-wide x-strip, 2 z-planes (z0, z0+1) -> 16 outputs.
// 6 input planes per thread share row loads between the two z-accumulators.
// Weights: LDS broadcast (no register copy -> no spill). No data staging,
// no in-loop barriers.
// Block (20,16)=320 thr. Grid (160/16, 160/2, B) = (10, 80, 2).
// ---------------------------------------------------------------------------
__global__ __launch_bounds__(320) void conv3d_g(
    const float* __restrict__ x, const float* __restrict__ w,
    float* __restrict__ y)
{
    __shared__ float wl[125];
    {
        const int tid = threadIdx.y * 20 + threadIdx.x;
        if (tid < 125) wl[tid] = w[tid];
    }
    __syncthreads();

    const int tx  = threadIdx.x;              // 0..19
    const int ty  = threadIdx.y;              // 0..15
    const int x0  = tx * 8;
    const int yy0 = blockIdx.x * 16 + ty;
    const int z0  = blockIdx.y * 2;
    const int b   = blockIdx.z;
    const float* xb = x + (size_t)b * VOL;

    const bool eL = (tx == 0), eR = (tx == 19);
    const int xa = eL ? 0 : (x0 - 2);
    const int xc = eR ? (DIMN - 4) : (x0 + 6);

    float acc0[8], acc1[8];
#pragma unroll
    for (int t = 0; t < 8; ++t) { acc0[t] = 0.f; acc1[t] = 0.f; }

#pragma unroll
    for (int j = 0; j < 6; ++j) {
        const int zz = iclampi(z0 - 2 + j, 0, DIMN - 1);
#pragma unroll
        for (int ky = 0; ky < 5; ++ky) {
            const int yy = iclampi(yy0 - 2 + ky, 0, DIMN - 1);
            const float* row = xb + ((size_t)zz * DIMN + yy) * DIMN;
            const float4 A = *(const float4*)(row + xa);
            const float4 B = *(const float4*)(row + x0 + 2);
            const float4 C = *(const float4*)(row + xc);
            // V[i] <-> x index clamp(x0-2+i), i = 0..11
            float V[12];
            V[0]  = A.x;
            V[1]  = eL ? A.x : A.y;
            V[2]  = eL ? A.x : A.z;
            V[3]  = eL ? A.y : A.w;
            V[4]  = B.x; V[5] = B.y; V[6] = B.z; V[7] = B.w;
            V[8]  = eR ? C.z : C.x;
            V[9]  = eR ? C.w : C.y;
            V[10] = eR ? C.w : C.z;
            V[11] = C.w;
#pragma unroll
            for (int kx = 0; kx < 5; ++kx) {
                if (j < 5) {   // output z0: kz = j
                    const float wa = wl[(j * 5 + ky) * 5 + kx];
#pragma unroll
                    for (int t = 0; t < 8; ++t)
                        acc0[t] = fmaf(wa, V[kx + t], acc0[t]);
                }
                if (j >= 1) {  // output z0+1: kz = j-1
                    const float wb = wl[((j - 1) * 5 + ky) * 5 + kx];
#pragma unroll
                    for (int t = 0; t < 8; ++t)
                        acc1[t] = fmaf(wb, V[kx + t], acc1[t]);
                }
            }
        }
    }

    float* yr0 = y + (((size_t)b * DIMN + z0)     * DIMN + yy0) * DIMN + x0;
    float* yr1 = y + (((size_t)b * DIMN + z0 + 1) * DIMN + yy0) * DIMN + x0;
    *(float4*)(yr0)     = make_float4(acc0[0], acc0[1], acc0[2], acc0[3]);
    *(float4*)(yr0 + 4) = make_float4(acc0[4], acc0[5], acc0[6], acc0[7]);
    *(float4*)(yr1)     = make_float4(acc1[0], acc1[1], acc1[2], acc1[3]);
    *(float4*)(yr1 + 4) = make_float4(acc1[4], acc1[5], acc1[6], acc1[7]);
}

// ---------------------------------------------------------------------------
// Kernel B: Hessian (jnp.gradient twice) + MLP, strip-4.
// h-computation identical to the verified round-2/4 kernel. MLP weights
// staged in LDS (broadcast reads), oo-outer loop reuses each weight across
// the 4-strip.
// ---------------------------------------------------------------------------
__global__ __launch_bounds__(256) void hess_mlp4(
    const float* __restrict__ Yg,
    const float* __restrict__ w1, const float* __restrict__ b1,
    const float* __restrict__ w2, const float* __restrict__ b2,
    float* __restrict__ out)
{
    __shared__ float wlds[81];  // w1[0..59], b1[60..69], w2[70..79], b2[80]
    {
        const int tid = threadIdx.x;
        if (tid < 60) wlds[tid] = w1[tid];
        if (tid >= 60 && tid < 70) wlds[tid] = b1[tid - 60];
        if (tid >= 70 && tid < 80) wlds[tid] = w2[tid - 70];
        if (tid == 80) wlds[80] = b2[0];
    }
    __syncthreads();

    const int sid = blockIdx.x * 256 + threadIdx.x;   // strip id, < 2,048,000
    const int rrow = sid / 40;                        // row over (b,z,y)
    const int x0 = (sid - rrow * 40) * 4;
    const int b = rrow / (DIMN * DIMN);
    int rem = rrow - b * (DIMN * DIMN);
    const int z = rem / DIMN;
    const int y = rem - z * DIMN;

    const float* Yb = Yg + (size_t)b * VOL;
    const int zp1 = min(z + 1, DIMN - 1), zm1 = max(z - 1, 0);
    const int zp2 = min(z + 2, DIMN - 1), zm2 = max(z - 2, 0);
    const int yp1 = min(y + 1, DIMN - 1), ym1 = max(y - 1, 0);
    const int yp2 = min(y + 2, DIMN - 1), ym2 = max(y - 2, 0);

    auto rowp = [&](int zz, int yy) { return Yb + ((size_t)zz * DIMN + yy) * DIMN; };

    const int xl = max(x0 - 2, 0);
    const int xr = (x0 < DIMN - 4) ? (x0 + 4) : (DIMN - 2);
    const bool xL = (x0 > 0), xR = (x0 < DIMN - 4);

    const float* Rc = rowp(z, y);
    float4 Cc = *(const float4*)(Rc + x0);
    float2 Cl = *(const float2*)(Rc + xl);
    float2 Cr = *(const float2*)(Rc + xr);
    const float* Rzp = rowp(zp1, y);
    float4 Pzc = *(const float4*)(Rzp + x0);
    float2 Pzl = *(const float2*)(Rzp + xl);
    float2 Pzr = *(const float2*)(Rzp + xr);
    const float* Rzm = rowp(zm1, y);
    float4 Mzc = *(const float4*)(Rzm + x0);
    float2 Mzl = *(const float2*)(Rzm + xl);
    float2 Mzr = *(const float2*)(Rzm + xr);
    const float* Ryp = rowp(z, yp1);
    float4 Pyc = *(const float4*)(Ryp + x0);
    float2 Pyl = *(const float2*)(Ryp + xl);
    float2 Pyr = *(const float2*)(Ryp + xr);
    const float* Rym = rowp(z, ym1);
    float4 Myc = *(const float4*)(Rym + x0);
    float2 Myl = *(const float2*)(Rym + xl);
    float2 Myr = *(const float2*)(Rym + xr);
    float4 Z2p = *(const float4*)(rowp(zp2, y) + x0);
    float4 Z2m = *(const float4*)(rowp(zm2, y) + x0);
    float4 Y2p = *(const float4*)(rowp(z, yp2) + x0);
    float4 Y2m = *(const float4*)(rowp(z, ym2) + x0);
    float4 Dpp = *(const float4*)(rowp(zp1, yp1) + x0);
    float4 Dpm = *(const float4*)(rowp(zp1, ym1) + x0);
    float4 Dmp = *(const float4*)(rowp(zm1, yp1) + x0);
    float4 Dmm = *(const float4*)(rowp(zm1, ym1) + x0);

    float V[8];
    V[0] = Cl.x;
    V[1] = xL ? Cl.y : Cl.x;
    V[2] = Cc.x; V[3] = Cc.y; V[4] = Cc.z; V[5] = Cc.w;
    V[6] = xR ? Cr.x : Cr.y;
    V[7] = Cr.y;
    float PZ[6], MZ[6], PY[6], MY[6];
    PZ[0] = xL ? Pzl.y : Pzl.x; PZ[1] = Pzc.x; PZ[2] = Pzc.y; PZ[3] = Pzc.z; PZ[4] = Pzc.w; PZ[5] = xR ? Pzr.x : Pzr.y;
    MZ[0] = xL ? Mzl.y : Mzl.x; MZ[1] = Mzc.x; MZ[2] = Mzc.y; MZ[3] = Mzc.z; MZ[4] = Mzc.w; MZ[5] = xR ? Mzr.x : Mzr.y;
    PY[0] = xL ? Pyl.y : Pyl.x; PY[1] = Pyc.x; PY[2] = Pyc.y; PY[3] = Pyc.z; PY[4] = Pyc.w; PY[5] = xR ? Pyr.x : Pyr.y;
    MY[0] = xL ? Myl.y : Myl.x; MY[1] = Myc.x; MY[2] = Myc.y; MY[3] = Myc.z; MY[4] = Myc.w; MY[5] = xR ? Myr.x : Myr.y;
    float C4[4]  = {Cc.x, Cc.y, Cc.z, Cc.w};
    float Z2P[4] = {Z2p.x, Z2p.y, Z2p.z, Z2p.w};
    float Z2M[4] = {Z2m.x, Z2m.y, Z2m.z, Z2m.w};
    float Y2P[4] = {Y2p.x, Y2p.y, Y2p.z, Y2p.w};
    float Y2M[4] = {Y2m.x, Y2m.y, Y2m.z, Y2m.w};
    float DPP[4] = {Dpp.x, Dpp.y, Dpp.z, Dpp.w};
    float DPM[4] = {Dpm.x, Dpm.y, Dpm.z, Dpm.w};
    float DMP[4] = {Dmp.x, Dmp.y, Dmp.z, Dmp.w};
    float DMM[4] = {Dmm.x, Dmm.y, Dmm.z, Dmm.w};

    const float sz1 = (z > 0 && z < DIMN - 1) ? 0.5f : 1.0f;
    const float szp = (z < DIMN - 2) ? 0.5f : 1.0f;
    const float szm = (z > 1) ? 0.5f : 1.0f;
    const float sy1 = (y > 0 && y < DIMN - 1) ? 0.5f : 1.0f;
    const float syp = (y < DIMN - 2) ? 0.5f : 1.0f;
    const float sym = (y > 1) ? 0.5f : 1.0f;
    const bool zTop = (z == DIMN - 1), zBot = (z == 0);
    const bool yTop = (y == DIMN - 1), yBot = (y == 0);

    // ---- h values for the 4-strip ----
    float H0[4], H1[4], H2[4], H3[4], H4[4], H5[4];
#pragma unroll
    for (int t = 0; t < 4; ++t) {
        const int xx = x0 + t;
        const float sx1 = (xx > 0 && xx < DIMN - 1) ? 0.5f : 1.0f;
        const float sxp = (xx < DIMN - 2) ? 0.5f : 1.0f;
        const float sxm = (xx > 1) ? 0.5f : 1.0f;

        {   // d2/dz2
            const float B0 = zTop ? MZ[t + 1] : C4[t];
            const float C0 = zBot ? PZ[t + 1] : C4[t];
            H0[t] = sz1 * (szp * (Z2P[t] - B0) - szm * (C0 - Z2M[t]));
        }
        H1[t] = sy1 * sz1 * ((DPP[t] - DMP[t]) - (DPM[t] - DMM[t]));
        H2[t] = sx1 * sz1 * ((PZ[t + 2] - MZ[t + 2]) - (PZ[t] - MZ[t]));
        {   // d2/dy2
            const float B3 = yTop ? MY[t + 1] : C4[t];
            const float C3 = yBot ? PY[t + 1] : C4[t];
            H3[t] = sy1 * (syp * (Y2P[t] - B3) - sym * (C3 - Y2M[t]));
        }
        H4[t] = sx1 * sy1 * ((PY[t + 2] - MY[t + 2]) - (PY[t] - MY[t]));
        {   // d2/dx2
            const float aP = (xx == DIMN - 1) ? V[t + 1] : V[t + 2];
            const float cM = (xx == 0) ? V[t + 3] : V[t + 2];
            H5[t] = sx1 * (sxp * (V[t + 4] - aP) - sxm * (cM - V[t]));
        }
    }

    // ---- MLP: oo-outer, LDS-broadcast weights reused across the strip ----
    float o[4];
    {
        const float bb2 = wlds[80];
#pragma unroll
        for (int t = 0; t < 4; ++t) o[t] = bb2;
    }
#pragma unroll
    for (int oo = 0; oo < 10; ++oo) {
        const float wr0 = wlds[oo * 6 + 0];
        const float wr1 = wlds[oo * 6 + 1];
        const float wr2 = wlds[oo * 6 + 2];
        const float wr3 = wlds[oo * 6 + 3];
        const float wr4 = wlds[oo * 6 + 4];
        const float wr5 = wlds[oo * 6 + 5];
        const float bb  = wlds[60 + oo];
        const float w2v = wlds[70 + oo];
#pragma unroll
        for (int t = 0; t < 4; ++t) {
            float a = bb;
            a = fmaf(H0[t], wr0, a);
            a = fmaf(H1[t], wr1, a);
            a = fmaf(H2[t], wr2, a);
            a = fmaf(H3[t], wr3, a);
            a = fmaf(H4[t], wr4, a);
            a = fmaf(H5[t], wr5, a);
            a = fmaxf(a, 0.f);
            o[t] = fmaf(a, w2v, o[t]);
        }
    }

    float res[4];
#pragma unroll
    for (int t = 0; t < 4; ++t) res[t] = 1.0f / (1.0f + __expf(-o[t]));
    *(float4*)(out + (size_t)sid * 4) =
        make_float4(res[0], res[1], res[2], res[3]);
}

// ---------------------------------------------------------------------------
extern "C" void kernel_launch(void* const* d_in, const int* in_sizes, int n_in,
                              void* d_out, int out_size, void* d_ws, size_t ws_size,
                              hipStream_t stream)
{
    const float* x  = (const float*)d_in[0];
    const float* cw = (const float*)d_in[1];
    const float* w1 = (const float*)d_in[2];
    const float* b1 = (const float*)d_in[3];
    const float* w2 = (const float*)d_in[4];
    const float* b2 = (const float*)d_in[5];
    float* outp = (float*)d_out;
    float* yws  = (float*)d_ws;

    dim3 blkA(20, 16, 1);
    dim3 grdA(DIMN / 16, DIMN / 2, BATCH);    // (10, 80, 2) = 1600 blocks
    conv3d_g<<<grdA, blkA, 0, stream>>>(x, cw, yws);

    const int nblkB = (int)(NPTS / 4 / 256);  // 8000
    hess_mlp4<<<nblkB, 256, 0, stream>>>(yws, w1, b1, w2, b2, outp);
}

// Round 6
// 167.552 us; speedup vs baseline: 2.0079x; 1.0416x over previous
//
#include <hip/hip_runtime.h>

constexpr int DIMN = 160;
constexpr int VOL  = DIMN * DIMN * DIMN;   // 4,096,000
constexpr int BATCH = 2;
constexpr long long NPTS = (long long)BATCH * VOL;

__device__ __forceinline__ int iclampi(int v, int lo, int hi) {
    return v < lo ? lo : (v > hi ? hi : v);
}

// ---------------------------------------------------------------------------
// Kernel A: gather-formulation 5x5x5 conv, replicate pad.
// Thread: 8-wide x-strip x 2 z-planes -> 16 outputs (inner loop identical to
// the round-5 verified conv3d_g). Mapping changed to FLAT 256-thread blocks:
// 320-thread blocks measured 12% occupancy vs 71% for 256-thread (r4/r5).
// Grid: 512000 threads / 256 = 2000 blocks.
// ---------------------------------------------------------------------------
__global__ __launch_bounds__(256) void conv3d_g2(
    const float* __restrict__ x, const float* __restrict__ w,
    float* __restrict__ y)
{
    __shared__ float wl[125];
    if (threadIdx.x < 125) wl[threadIdx.x] = w[threadIdx.x];
    __syncthreads();

    const int sid = blockIdx.x * 256 + threadIdx.x;
    const int xs  = sid % 20;            // x-strip
    int r = sid / 20;
    const int yy0 = r % DIMN;            // H row
    r /= DIMN;
    const int zp = r % 80;               // z-pair
    const int b  = r / 80;

    const int x0 = xs * 8;
    const int z0 = zp * 2;
    const float* xb = x + (size_t)b * VOL;

    const bool eL = (xs == 0), eR = (xs == 19);
    const int xa = eL ? 0 : (x0 - 2);
    const int xc = eR ? (DIMN - 4) : (x0 + 6);

    float acc0[8], acc1[8];
#pragma unroll
    for (int t = 0; t < 8; ++t) { acc0[t] = 0.f; acc1[t] = 0.f; }

#pragma unroll
    for (int j = 0; j < 6; ++j) {
        const int zz = iclampi(z0 - 2 + j, 0, DIMN - 1);
#pragma unroll
        for (int ky = 0; ky < 5; ++ky) {
            const int yy = iclampi(yy0 - 2 + ky, 0, DIMN - 1);
            const float* row = xb + ((size_t)zz * DIMN + yy) * DIMN;
            const float4 A = *(const float4*)(row + xa);
            const float4 B = *(const float4*)(row + x0 + 2);
            const float4 C = *(const float4*)(row + xc);
            // V[i] <-> x index clamp(x0-2+i), i = 0..11
            float V[12];
            V[0]  = A.x;
            V[1]  = eL ? A.x : A.y;
            V[2]  = eL ? A.x : A.z;
            V[3]  = eL ? A.y : A.w;
            V[4]  = B.x; V[5] = B.y; V[6] = B.z; V[7] = B.w;
            V[8]  = eR ? C.z : C.x;
            V[9]  = eR ? C.w : C.y;
            V[10] = eR ? C.w : C.z;
            V[11] = C.w;
#pragma unroll
            for (int kx = 0; kx < 5; ++kx) {
                if (j < 5) {   // output z0: kz = j
                    const float wa = wl[(j * 5 + ky) * 5 + kx];
#pragma unroll
                    for (int t = 0; t < 8; ++t)
                        acc0[t] = fmaf(wa, V[kx + t], acc0[t]);
                }
                if (j >= 1) {  // output z0+1: kz = j-1
                    const float wb = wl[((j - 1) * 5 + ky) * 5 + kx];
#pragma unroll
                    for (int t = 0; t < 8; ++t)
                        acc1[t] = fmaf(wb, V[kx + t], acc1[t]);
                }
            }
        }
    }

    float* yr0 = y + (((size_t)b * DIMN + z0)     * DIMN + yy0) * DIMN + x0;
    float* yr1 = y + (((size_t)b * DIMN + z0 + 1) * DIMN + yy0) * DIMN + x0;
    *(float4*)(yr0)     = make_float4(acc0[0], acc0[1], acc0[2], acc0[3]);
    *(float4*)(yr0 + 4) = make_float4(acc0[4], acc0[5], acc0[6], acc0[7]);
    *(float4*)(yr1)     = make_float4(acc1[0], acc1[1], acc1[2], acc1[3]);
    *(float4*)(yr1 + 4) = make_float4(acc1[4], acc1[5], acc1[6], acc1[7]);
}

// ---------------------------------------------------------------------------
// Kernel B: Hessian (jnp.gradient twice) + MLP, strip-4.  (unchanged,
// verified r5 — left intact so its counters surface once conv drops)
// ---------------------------------------------------------------------------
__global__ __launch_bounds__(256) void hess_mlp4(
    const float* __restrict__ Yg,
    const float* __restrict__ w1, const float* __restrict__ b1,
    const float* __restrict__ w2, const float* __restrict__ b2,
    float* __restrict__ out)
{
    __shared__ float wlds[81];  // w1[0..59], b1[60..69], w2[70..79], b2[80]
    {
        const int tid = threadIdx.x;
        if (tid < 60) wlds[tid] = w1[tid];
        if (tid >= 60 && tid < 70) wlds[tid] = b1[tid - 60];
        if (tid >= 70 && tid < 80) wlds[tid] = w2[tid - 70];
        if (tid == 80) wlds[80] = b2[0];
    }
    __syncthreads();

    const int sid = blockIdx.x * 256 + threadIdx.x;   // strip id, < 2,048,000
    const int rrow = sid / 40;                        // row over (b,z,y)
    const int x0 = (sid - rrow * 40) * 4;
    const int b = rrow / (DIMN * DIMN);
    int rem = rrow - b * (DIMN * DIMN);
    const int z = rem / DIMN;
    const int y = rem - z * DIMN;

    const float* Yb = Yg + (size_t)b * VOL;
    const int zp1 = min(z + 1, DIMN - 1), zm1 = max(z - 1, 0);
    const int zp2 = min(z + 2, DIMN - 1), zm2 = max(z - 2, 0);
    const int yp1 = min(y + 1, DIMN - 1), ym1 = max(y - 1, 0);
    const int yp2 = min(y + 2, DIMN - 1), ym2 = max(y - 2, 0);

    auto rowp = [&](int zz, int yy) { return Yb + ((size_t)zz * DIMN + yy) * DIMN; };

    const int xl = max(x0 - 2, 0);
    const int xr = (x0 < DIMN - 4) ? (x0 + 4) : (DIMN - 2);
    const bool xL = (x0 > 0), xR = (x0 < DIMN - 4);

    const float* Rc = rowp(z, y);
    float4 Cc = *(const float4*)(Rc + x0);
    float2 Cl = *(const float2*)(Rc + xl);
    float2 Cr = *(const float2*)(Rc + xr);
    const float* Rzp = rowp(zp1, y);
    float4 Pzc = *(const float4*)(Rzp + x0);
    float2 Pzl = *(const float2*)(Rzp + xl);
    float2 Pzr = *(const float2*)(Rzp + xr);
    const float* Rzm = rowp(zm1, y);
    float4 Mzc = *(const float4*)(Rzm + x0);
    float2 Mzl = *(const float2*)(Rzm + xl);
    float2 Mzr = *(const float2*)(Rzm + xr);
    const float* Ryp = rowp(z, yp1);
    float4 Pyc = *(const float4*)(Ryp + x0);
    float2 Pyl = *(const float2*)(Ryp + xl);
    float2 Pyr = *(const float2*)(Ryp + xr);
    const float* Rym = rowp(z, ym1);
    float4 Myc = *(const float4*)(Rym + x0);
    float2 Myl = *(const float2*)(Rym + xl);
    float2 Myr = *(const float2*)(Rym + xr);
    float4 Z2p = *(const float4*)(rowp(zp2, y) + x0);
    float4 Z2m = *(const float4*)(rowp(zm2, y) + x0);
    float4 Y2p = *(const float4*)(rowp(z, yp2) + x0);
    float4 Y2m = *(const float4*)(rowp(z, ym2) + x0);
    float4 Dpp = *(const float4*)(rowp(zp1, yp1) + x0);
    float4 Dpm = *(const float4*)(rowp(zp1, ym1) + x0);
    float4 Dmp = *(const float4*)(rowp(zm1, yp1) + x0);
    float4 Dmm = *(const float4*)(rowp(zm1, ym1) + x0);

    float V[8];
    V[0] = Cl.x;
    V[1] = xL ? Cl.y : Cl.x;
    V[2] = Cc.x; V[3] = Cc.y; V[4] = Cc.z; V[5] = Cc.w;
    V[6] = xR ? Cr.x : Cr.y;
    V[7] = Cr.y;
    float PZ[6], MZ[6], PY[6], MY[6];
    PZ[0] = xL ? Pzl.y : Pzl.x; PZ[1] = Pzc.x; PZ[2] = Pzc.y; PZ[3] = Pzc.z; PZ[4] = Pzc.w; PZ[5] = xR ? Pzr.x : Pzr.y;
    MZ[0] = xL ? Mzl.y : Mzl.x; MZ[1] = Mzc.x; MZ[2] = Mzc.y; MZ[3] = Mzc.z; MZ[4] = Mzc.w; MZ[5] = xR ? Mzr.x : Mzr.y;
    PY[0] = xL ? Pyl.y : Pyl.x; PY[1] = Pyc.x; PY[2] = Pyc.y; PY[3] = Pyc.z; PY[4] = Pyc.w; PY[5] = xR ? Pyr.x : Pyr.y;
    MY[0] = xL ? Myl.y : Myl.x; MY[1] = Myc.x; MY[2] = Myc.y; MY[3] = Myc.z; MY[4] = Myc.w; MY[5] = xR ? Myr.x : Myr.y;
    float C4[4]  = {Cc.x, Cc.y, Cc.z, Cc.w};
    float Z2P[4] = {Z2p.x, Z2p.y, Z2p.z, Z2p.w};
    float Z2M[4] = {Z2m.x, Z2m.y, Z2m.z, Z2m.w};
    float Y2P[4] = {Y2p.x, Y2p.y, Y2p.z, Y2p.w};
    float Y2M[4] = {Y2m.x, Y2m.y, Y2m.z, Y2m.w};
    float DPP[4] = {Dpp.x, Dpp.y, Dpp.z, Dpp.w};
    float DPM[4] = {Dpm.x, Dpm.y, Dpm.z, Dpm.w};
    float DMP[4] = {Dmp.x, Dmp.y, Dmp.z, Dmp.w};
    float DMM[4] = {Dmm.x, Dmm.y, Dmm.z, Dmm.w};

    const float sz1 = (z > 0 && z < DIMN - 1) ? 0.5f : 1.0f;
    const float szp = (z < DIMN - 2) ? 0.5f : 1.0f;
    const float szm = (z > 1) ? 0.5f : 1.0f;
    const float sy1 = (y > 0 && y < DIMN - 1) ? 0.5f : 1.0f;
    const float syp = (y < DIMN - 2) ? 0.5f : 1.0f;
    const float sym = (y > 1) ? 0.5f : 1.0f;
    const bool zTop = (z == DIMN - 1), zBot = (z == 0);
    const bool yTop = (y == DIMN - 1), yBot = (y == 0);

    float H0[4], H1[4], H2[4], H3[4], H4[4], H5[4];
#pragma unroll
    for (int t = 0; t < 4; ++t) {
        const int xx = x0 + t;
        const float sx1 = (xx > 0 && xx < DIMN - 1) ? 0.5f : 1.0f;
        const float sxp = (xx < DIMN - 2) ? 0.5f : 1.0f;
        const float sxm = (xx > 1) ? 0.5f : 1.0f;

        {
            const float B0 = zTop ? MZ[t + 1] : C4[t];
            const float C0 = zBot ? PZ[t + 1] : C4[t];
            H0[t] = sz1 * (szp * (Z2P[t] - B0) - szm * (C0 - Z2M[t]));
        }
        H1[t] = sy1 * sz1 * ((DPP[t] - DMP[t]) - (DPM[t] - DMM[t]));
        H2[t] = sx1 * sz1 * ((PZ[t + 2] - MZ[t + 2]) - (PZ[t] - MZ[t]));
        {
            const float B3 = yTop ? MY[t + 1] : C4[t];
            const float C3 = yBot ? PY[t + 1] : C4[t];
            H3[t] = sy1 * (syp * (Y2P[t] - B3) - sym * (C3 - Y2M[t]));
        }
        H4[t] = sx1 * sy1 * ((PY[t + 2] - MY[t + 2]) - (PY[t] - MY[t]));
        {
            const float aP = (xx == DIMN - 1) ? V[t + 1] : V[t + 2];
            const float cM = (xx == 0) ? V[t + 3] : V[t + 2];
            H5[t] = sx1 * (sxp * (V[t + 4] - aP) - sxm * (cM - V[t]));
        }
    }

    float o[4];
    {
        const float bb2 = wlds[80];
#pragma unroll
        for (int t = 0; t < 4; ++t) o[t] = bb2;
    }
#pragma unroll
    for (int oo = 0; oo < 10; ++oo) {
        const float wr0 = wlds[oo * 6 + 0];
        const float wr1 = wlds[oo * 6 + 1];
        const float wr2 = wlds[oo * 6 + 2];
        const float wr3 = wlds[oo * 6 + 3];
        const float wr4 = wlds[oo * 6 + 4];
        const float wr5 = wlds[oo * 6 + 5];
        const float bb  = wlds[60 + oo];
        const float w2v = wlds[70 + oo];
#pragma unroll
        for (int t = 0; t < 4; ++t) {
            float a = bb;
            a = fmaf(H0[t], wr0, a);
            a = fmaf(H1[t], wr1, a);
            a = fmaf(H2[t], wr2, a);
            a = fmaf(H3[t], wr3, a);
            a = fmaf(H4[t], wr4, a);
            a = fmaf(H5[t], wr5, a);
            a = fmaxf(a, 0.f);
            o[t] = fmaf(a, w2v, o[t]);
        }
    }

    float res[4];
#pragma unroll
    for (int t = 0; t < 4; ++t) res[t] = 1.0f / (1.0f + __expf(-o[t]));
    *(float4*)(out + (size_t)sid * 4) =
        make_float4(res[0], res[1], res[2], res[3]);
}

// ---------------------------------------------------------------------------
extern "C" void kernel_launch(void* const* d_in, const int* in_sizes, int n_in,
                              void* d_out, int out_size, void* d_ws, size_t ws_size,
                              hipStream_t stream)
{
    const float* x  = (const float*)d_in[0];
    const float* cw = (const float*)d_in[1];
    const float* w1 = (const float*)d_in[2];
    const float* b1 = (const float*)d_in[3];
    const float* w2 = (const float*)d_in[4];
    const float* b2 = (const float*)d_in[5];
    float* outp = (float*)d_out;
    float* yws  = (float*)d_ws;

    const int nblkA = (int)(NPTS / 16 / 256);  // 2000 blocks (16 outputs/thread)
    conv3d_g2<<<nblkA, 256, 0, stream>>>(x, cw, yws);

    const int nblkB = (int)(NPTS / 4 / 256);   // 8000
    hess_mlp4<<<nblkB, 256, 0, stream>>>(yws, w1, b1, w2, b2, outp);
}